// Round 2
// baseline (164.380 us; speedup 1.0000x reference)
//
#include <hip/hip_runtime.h>

// MoE dense: N=16384, D=256, E=8, H=128.
// R10: k_moe pipeline rebuild. R9 measured 64us with MfmaUtil 21.7%:
// LDS-BW-bound (96 ds_read_b128 + 32KB stage/chunk) + barrier drain
// (__syncthreads emits vmcnt(0), killing the 1-chunk prefetch). Changes:
//  - x fragments held in 64 VGPRs (loaded once from the x-tile staged in
//    Ws[2]), reused across all 8 experts: phase-1 reads 12->8/wave/chunk,
//    and frees 32KB -> Ws becomes a TRIPLE buffer.
//  - counted-vmcnt schedule (T3+T4): raw s_barrier + s_waitcnt vmcnt(4)
//    lgkmcnt(0); prefetch depth 2 (STAGE T+2 at chunk T); dummy stages at
//    T=62/63 keep the count invariant; all other global loads hoisted out
//    of the loop so vmcnt counts exactly the 4 STAGE gl2lds.
//  - s_setprio(1) around MFMA clusters (T5).
// Workspace:
//   xb   [16384][256] bf16 @ 0
//   w1t  [8][256][256] bf16 @ 8388608   (w1t[e][h][c] = W1[e][c][h])
//   wg1t [128][256] bf16 @ 9437184      (wg1t[h][c] = Wg1[c][h])
//   w2t  [256][2048] bf16 @ 9502720     (w2t[d][e*256+h] = W2[e][h][d])
//   g    [16384][8] f32 @ 10584064

typedef unsigned short USH;
typedef float f32x4 __attribute__((ext_vector_type(4)));
typedef __bf16 bf16x8 __attribute__((ext_vector_type(8)));

#define AS1 __attribute__((address_space(1)))
#define AS3 __attribute__((address_space(3)))

__device__ __forceinline__ USH f2bf(float f) {
  unsigned int u = __float_as_uint(f);
  u += 0x7fffu + ((u >> 16) & 1u);   // RNE
  return (USH)(u >> 16);
}

__device__ __forceinline__ void gl2lds16(const void* g, void* l) {
  __builtin_amdgcn_global_load_lds((AS1 const void*)g, (AS3 void*)l, 16, 0, 0);
}

// counted-vmcnt chunk sync: leave the in-flight next-chunk stage (4 loads)
// pending; drain LDS ops so ds_writes are visible and frag reads are done.
#define CHUNK_SYNC() do { \
  __builtin_amdgcn_sched_barrier(0); \
  asm volatile("s_waitcnt vmcnt(4) lgkmcnt(0)" ::: "memory"); \
  __builtin_amdgcn_s_barrier(); \
  __builtin_amdgcn_sched_barrier(0); } while (0)

// ---------------- prep ----------------

__global__ __launch_bounds__(256) void k_prep(
    const float* __restrict__ x,
    const float* __restrict__ Wg1,
    const float* __restrict__ W1,
    const float* __restrict__ W2,
    USH* __restrict__ xb, USH* __restrict__ wg1t,
    USH* __restrict__ w1t, USH* __restrict__ w2t) {
  __shared__ float T[64][65];
  int b = blockIdx.x, tid = threadIdx.x;

  if (b < 2048) {               // xb: flat coalesced cast
    size_t i8 = ((size_t)b * 256 + tid) * 8;
    float4 a = *(const float4*)(x + i8);
    float4 c = *(const float4*)(x + i8 + 4);
    USH v[8];
    v[0] = f2bf(a.x); v[1] = f2bf(a.y); v[2] = f2bf(a.z); v[3] = f2bf(a.w);
    v[4] = f2bf(c.x); v[5] = f2bf(c.y); v[6] = f2bf(c.z); v[7] = f2bf(c.w);
    *(uint4*)(xb + i8) = *(const uint4*)v;
  } else if (b < 2176) {        // w1t[e][h][c] = W1[e][c][h]
    int bp = b - 2048;
    int e = bp >> 4, tl = bp & 15;
    int c0 = (tl >> 2) * 64, h0 = (tl & 3) * 64;
    const float* src = W1 + (size_t)e * 65536;
#pragma unroll
    for (int p = 0; p < 4; ++p) {
      int r = p * 16 + (tid >> 4), d4 = (tid & 15) * 4;
      float4 v = *(const float4*)(src + (size_t)(c0 + r) * 256 + h0 + d4);
      T[r][d4] = v.x; T[r][d4 + 1] = v.y; T[r][d4 + 2] = v.z; T[r][d4 + 3] = v.w;
    }
    __syncthreads();
#pragma unroll
    for (int p = 0; p < 4; ++p) {
      int hr = p * 16 + (tid >> 4), c4 = (tid & 15) * 4;
      USH w[4];
#pragma unroll
      for (int j = 0; j < 4; ++j) w[j] = f2bf(T[c4 + j][hr]);
      *(uint2*)(w1t + (size_t)e * 65536 + (size_t)(h0 + hr) * 256 + c0 + c4) = *(const uint2*)w;
    }
  } else if (b < 2184) {        // wg1t[h][c] = Wg1[c][h]
    int bp = b - 2176;
    int c0 = (bp >> 1) * 64, h0 = (bp & 1) * 64;
#pragma unroll
    for (int p = 0; p < 4; ++p) {
      int r = p * 16 + (tid >> 4), d4 = (tid & 15) * 4;
      float4 v = *(const float4*)(Wg1 + (size_t)(c0 + r) * 128 + h0 + d4);
      T[r][d4] = v.x; T[r][d4 + 1] = v.y; T[r][d4 + 2] = v.z; T[r][d4 + 3] = v.w;
    }
    __syncthreads();
#pragma unroll
    for (int p = 0; p < 4; ++p) {
      int hr = p * 16 + (tid >> 4), c4 = (tid & 15) * 4;
      USH w[4];
#pragma unroll
      for (int j = 0; j < 4; ++j) w[j] = f2bf(T[c4 + j][hr]);
      *(uint2*)(wg1t + (size_t)(h0 + hr) * 256 + c0 + c4) = *(const uint2*)w;
    }
  } else {                      // w2t[d][e*256+h] = W2[e][h][d]
    int bp = b - 2184;
    int e = bp >> 4, tl = bp & 15;
    int h0 = (tl >> 2) * 64, d0 = (tl & 3) * 64;
    const float* src = W2 + (size_t)e * 65536;
#pragma unroll
    for (int p = 0; p < 4; ++p) {
      int r = p * 16 + (tid >> 4), d4 = (tid & 15) * 4;
      float4 v = *(const float4*)(src + (size_t)(h0 + r) * 256 + d0 + d4);
      T[r][d4] = v.x; T[r][d4 + 1] = v.y; T[r][d4 + 2] = v.z; T[r][d4 + 3] = v.w;
    }
    __syncthreads();
#pragma unroll
    for (int p = 0; p < 4; ++p) {
      int dr = p * 16 + (tid >> 4), h4 = (tid & 15) * 4;
      USH w[4];
#pragma unroll
      for (int j = 0; j < 4; ++j) w[j] = f2bf(T[h4 + j][dr]);
      *(uint2*)(w2t + (size_t)(d0 + dr) * 2048 + e * 256 + h0 + h4) = *(const uint2*)w;
    }
  }
}

// ---------------- gate (512 blocks x 32 rows, BK=64, swizzled) ----------------

__global__ __launch_bounds__(256) void k_gate(const USH* __restrict__ xb,
                                              const USH* __restrict__ wg1t,
                                              const float* __restrict__ bg1,
                                              const float* __restrict__ wg2,
                                              const float* __restrict__ bg2,
                                              float* __restrict__ g) {
  __shared__ __align__(16) USH As[32 * 64];
  __shared__ __align__(16) USH Bs[128 * 64];
  __shared__ float hg[32 * 129];
  __shared__ float bg1s[128];
  __shared__ float w2s[128 * 8];
  __shared__ float b2s[8];
  __shared__ float lg[32 * 8];

  int tid = threadIdx.x;
  int wave = tid >> 6, lane = tid & 63;
  int quad = lane >> 4, l16 = lane & 15;
  int sw = l16 & 7;
  int wr = wave >> 1, wc = wave & 1;
  int rowBase = blockIdx.x * 32;

  for (int t = tid; t < 1024; t += 256) w2s[t] = wg2[t];
  if (tid < 8) b2s[tid] = bg2[tid];
  if (tid < 128) bg1s[tid] = bg1[tid];

  f32x4 acc[4] = {};
  for (int kt = 0; kt < 4; ++kt) {
    int kb = kt * 64;
    {
      int r = tid >> 3, c8 = (tid & 7) ^ (r & 7);
      gl2lds16(xb + (size_t)(rowBase + r) * 256 + kb + c8 * 8, As + (size_t)tid * 8);
    }
#pragma unroll
    for (int c = 0; c < 4; ++c) {
      int i = c * 256 + tid;
      int r = i >> 3, c8 = (i & 7) ^ (r & 7);
      gl2lds16(wg1t + (size_t)r * 256 + kb + c8 * 8, Bs + (size_t)i * 8);
    }
    __syncthreads();
#pragma unroll
    for (int kkc = 0; kkc < 8; kkc += 4) {
      bf16x8 av = *(const bf16x8*)(As + (wr * 16 + l16) * 64 + (((kkc + quad) ^ sw) * 8));
#pragma unroll
      for (int j = 0; j < 4; ++j) {
        bf16x8 bv = *(const bf16x8*)(Bs + (wc * 64 + j * 16 + l16) * 64 + (((kkc + quad) ^ sw) * 8));
        acc[j] = __builtin_amdgcn_mfma_f32_16x16x32_bf16(av, bv, acc[j], 0, 0, 0);
      }
    }
    __syncthreads();
  }

#pragma unroll
  for (int j = 0; j < 4; ++j)
#pragma unroll
    for (int r = 0; r < 4; ++r) {
      int row = wr * 16 + quad * 4 + r;
      int col = wc * 64 + j * 16 + l16;
      hg[row * 129 + col] = fmaxf(acc[j][r] + bg1s[col], 0.0f);
    }
  __syncthreads();

  {
    int row = tid >> 3, p = tid & 7;
    float s = b2s[p];
    for (int k = 0; k < 128; ++k) s += hg[row * 129 + k] * w2s[k * 8 + p];
    lg[row * 8 + p] = s;
  }
  __syncthreads();

  if (tid < 32) {
    float l[8];
    float m = -1e30f;
#pragma unroll
    for (int e = 0; e < 8; ++e) { l[e] = lg[tid * 8 + e]; m = fmaxf(m, l[e]); }
    float s = 0.0f;
#pragma unroll
    for (int e = 0; e < 8; ++e) { l[e] = expf(l[e] - m); s += l[e]; }
    float inv = 1.0f / s;
    size_t grow = rowBase + tid;
#pragma unroll
    for (int e = 0; e < 8; ++e) g[grow * 8 + e] = l[e] * inv;
  }
}

// ---------------- fused experts (256 blocks x 64 rows, 512 thr) --------------

__global__ __launch_bounds__(512) void k_moe(const USH* __restrict__ xb,
                                             const USH* __restrict__ w1t,
                                             const USH* __restrict__ w2t,
                                             const float* __restrict__ b1,
                                             const float* __restrict__ b2,
                                             const float* __restrict__ g,
                                             float* __restrict__ out) {
  __shared__ __align__(16) USH Ws[3][256 * 64];   // 96KB weight triple buffer;
                                                  // Ws[2] holds the x tile at init
  __shared__ __align__(16) USH Hs[64 * 256];      // 32KB, swizzled
  __shared__ float b1s[2048];
  __shared__ float b2s[2048];
  __shared__ float gs[512];                       // gs[n*8+e]

  int tid = threadIdx.x;
  int wave = tid >> 6, lane = tid & 63;
  int quad = lane >> 4, l16 = lane & 15;
  int sw = l16 & 7;
  int rowBase = blockIdx.x * 64;

  // ---- prologue: x tile (64x256, swizzled) into Ws[2]; biases/gates to LDS
#pragma unroll
  for (int it = 0; it < 4; ++it) {
    int i = it * 512 + tid;
    int kt = i >> 9, rem = i & 511;
    int r = rem >> 3, slot = rem & 7;
    int c8 = slot ^ (r & 7);
    gl2lds16(xb + (size_t)(rowBase + r) * 256 + kt * 64 + c8 * 8, &Ws[2][0] + (size_t)i * 8);
  }
#pragma unroll
  for (int t = 0; t < 4; ++t) {
    b1s[t * 512 + tid] = b1[t * 512 + tid];
    b2s[t * 512 + tid] = b2[t * 512 + tid];
  }
  gs[tid] = g[(size_t)rowBase * 8 + tid];

  // drain everything once; after this, in-loop vmcnt == outstanding STAGEs only
  __builtin_amdgcn_sched_barrier(0);
  asm volatile("s_waitcnt vmcnt(0) lgkmcnt(0)" ::: "memory");
  __builtin_amdgcn_s_barrier();
  __builtin_amdgcn_sched_barrier(0);

  // chunk src in [0,64): e=src>>3; src&4: 0 = W1 c-chunk, 1 = W2 h-chunk
  auto STAGE = [&](int src, int bf) {
    int e = src >> 3;
    int cbo = (src & 3) * 64;
    const USH* sp;
    size_t stride;
    if (src & 4) { sp = w2t + e * 256 + cbo;           stride = 2048; }
    else         { sp = w1t + (size_t)e * 65536 + cbo; stride = 256;  }
    USH* dst = &Ws[bf][0];
#pragma unroll
    for (int it = 0; it < 4; ++it) {
      int i = it * 512 + tid;
      int r = i >> 3, slot = i & 7;
      int c8 = slot ^ (r & 7);
      gl2lds16(sp + (size_t)r * stride + c8 * 8, dst + (size_t)i * 8);
    }
  };

  int wh = wave >> 1, wn = wave & 1;    // phase-1: wave = 64h x 32n
  int wn2 = wave >> 2, wd = wave & 3;   // phase-2: wave = 32n x 64d

  STAGE(0, 0);
  STAGE(1, 1);

  // x fragments -> 64 VGPRs (reused by all 8 experts); reads drain at the
  // first CHUNK_SYNC's lgkmcnt(0), before Ws[2] is restaged (chunk T=2).
  bf16x8 xr[4][2][2];
#pragma unroll
  for (int kt = 0; kt < 4; ++kt)
#pragma unroll
    for (int c = 0; c < 2; ++c)
#pragma unroll
      for (int j = 0; j < 2; ++j)
        xr[kt][c][j] = *(const bf16x8*)(&Ws[2][0] + kt * 4096 +
                         (wn * 32 + j * 16 + l16) * 64 + (((c * 4 + quad) ^ sw) * 8));

  f32x4 oacc[2][4] = {};

#pragma unroll 1
  for (int e = 0; e < 8; ++e) {
    f32x4 hacc[4][2] = {};

    // phase 1: H^T[h,n] = sum_c W1[c,h] * x[n,c]
#pragma unroll
    for (int kt = 0; kt < 4; ++kt) {
      int T = e * 8 + kt;
      CHUNK_SYNC();                       // Ws[T%3] ready; T+1 still in flight
      STAGE((T + 2) & 63, (T + 2) % 3);   // &63: tail restages 0/1 (unread dummy)
      const USH* W = &Ws[T % 3][0];
      __builtin_amdgcn_s_setprio(1);
#pragma unroll
      for (int c = 0; c < 2; ++c) {
        int cs = ((c * 4 + quad) ^ sw) * 8;
        bf16x8 av[4];
#pragma unroll
        for (int i = 0; i < 4; ++i)
          av[i] = *(const bf16x8*)(W + (wh * 64 + i * 16 + l16) * 64 + cs);
#pragma unroll
        for (int i = 0; i < 4; ++i)
#pragma unroll
          for (int j = 0; j < 2; ++j)
            hacc[i][j] = __builtin_amdgcn_mfma_f32_16x16x32_bf16(av[i], xr[kt][c][j], hacc[i][j], 0, 0, 0);
      }
      __builtin_amdgcn_s_setprio(0);
    }

    // epilogue: Hs[n][h] = bf16(relu(hacc+b1)*g[n,e]); C[h,n]: 4 consecutive h
    // per reg quad -> ds_write_b64, directly in phase-2 A-frag layout.
#pragma unroll
    for (int i = 0; i < 4; ++i) {
      int c8 = i * 2 + (quad >> 1);
      int hb = wh * 64 + i * 16 + quad * 4;
#pragma unroll
      for (int j = 0; j < 2; ++j) {
        int n = wn * 32 + j * 16 + l16;
        float gg = gs[n * 8 + e];
        USH w4[4];
#pragma unroll
        for (int r = 0; r < 4; ++r)
          w4[r] = f2bf(fmaxf(hacc[i][j][r] + b1s[e * 256 + hb + r], 0.0f) * gg);
        int off = n * 256 + wh * 64 + (c8 ^ (n & 7)) * 8 + (quad & 1) * 4;
        *(uint2*)(Hs + off) = *(const uint2*)w4;
      }
    }

    // phase 2: out[n,d] += sum_h Hs[n,h] * W2[h,d]
#pragma unroll
    for (int ht = 0; ht < 4; ++ht) {
      int T = e * 8 + 4 + ht;
      CHUNK_SYNC();                       // Hs writes visible; Ws[T%3] ready
      STAGE((T + 2) & 63, (T + 2) % 3);
      const USH* W = &Ws[T % 3][0];
      __builtin_amdgcn_s_setprio(1);
#pragma unroll
      for (int c = 0; c < 2; ++c) {
        int cs = ((c * 4 + quad) ^ sw) * 8;
        bf16x8 av[2], bv[4];
#pragma unroll
        for (int i = 0; i < 2; ++i)
          av[i] = *(const bf16x8*)(Hs + (wn2 * 32 + i * 16 + l16) * 256 + ht * 64 + cs);
#pragma unroll
        for (int j = 0; j < 4; ++j)
          bv[j] = *(const bf16x8*)(W + (wd * 64 + j * 16 + l16) * 64 + cs);
#pragma unroll
        for (int i = 0; i < 2; ++i)
#pragma unroll
          for (int j = 0; j < 4; ++j)
            oacc[i][j] = __builtin_amdgcn_mfma_f32_16x16x32_bf16(av[i], bv[j], oacc[i][j], 0, 0, 0);
      }
      __builtin_amdgcn_s_setprio(0);
    }
  }

  // drain tail dummy stages before exit path
  asm volatile("s_waitcnt vmcnt(0)" ::: "memory");

  // final epilogue: out = oacc + sum_e g[n,e]*b2[e,d]  (exact f32 bias)
#pragma unroll
  for (int i = 0; i < 2; ++i)
#pragma unroll
    for (int r = 0; r < 4; ++r) {
      int n = wn2 * 32 + i * 16 + quad * 4 + r;
      const float* gr = gs + n * 8;
      size_t grow = (size_t)(rowBase + n) * 256;
#pragma unroll
      for (int j = 0; j < 4; ++j) {
        int d = wd * 64 + j * 16 + l16;
        float bias = 0.0f;
#pragma unroll
        for (int ee = 0; ee < 8; ++ee) bias += gr[ee] * b2s[ee * 256 + d];
        out[grow + d] = oacc[i][j][r] + bias;
      }
    }
}

// ---------------- launch ----------------

extern "C" void kernel_launch(void* const* d_in, const int* in_sizes, int n_in,
                              void* d_out, int out_size, void* d_ws, size_t ws_size,
                              hipStream_t stream) {
  const float* x   = (const float*)d_in[0];
  const float* Wg1 = (const float*)d_in[1];
  const float* bg1 = (const float*)d_in[2];
  const float* Wg2 = (const float*)d_in[3];
  const float* bg2 = (const float*)d_in[4];
  const float* W1  = (const float*)d_in[5];
  const float* b1  = (const float*)d_in[6];
  const float* W2  = (const float*)d_in[7];
  const float* b2  = (const float*)d_in[8];
  float* out = (float*)d_out;

  char* ws = (char*)d_ws;
  USH*   xb   = (USH*)(ws);
  USH*   w1t  = (USH*)(ws + 8388608);
  USH*   wg1t = (USH*)(ws + 9437184);
  USH*   w2t  = (USH*)(ws + 9502720);
  float* g    = (float*)(ws + 10584064);

  hipLaunchKernelGGL(k_prep, dim3(2312), dim3(256), 0, stream,
                     x, Wg1, W1, W2, xb, wg1t, w1t, w2t);
  hipLaunchKernelGGL(k_gate, dim3(512), dim3(256), 0, stream,
                     xb, wg1t, bg1, Wg2, bg2, g);
  hipLaunchKernelGGL(k_moe, dim3(256), dim3(512), 0, stream,
                     xb, w1t, w2t, b1, b2, g, out);
}

// Round 3
// 161.809 us; speedup vs baseline: 1.0159x; 1.0159x over previous
//
#include <hip/hip_runtime.h>

// MoE dense: N=16384, D=256, E=8, H=256 (expert hidden = D).
// R11: R10 minus the two schedule poisons. R10 (74us, MfmaUtil 17.9) bundled
// counted-vmcnt + xr-regs (good: bank conflicts 2.49M->1.9M) with
// sched_barrier(0) order-pinning (m141 poison: defeats compiler scheduling)
// and s_setprio on a lockstep barrier structure (m190 poison). This round
// removes ONLY the poisons -> clean attribution for the counted-vmcnt
// pipeline: CHUNK_SYNC = s_waitcnt vmcnt(4) lgkmcnt(0) + raw s_barrier,
// triple-buffered weight staging (prefetch depth 2), x fragments in 64 VGPRs
// reused across all 8 experts.
// Workspace:
//   xb   [16384][256] bf16 @ 0
//   w1t  [8][256][256] bf16 @ 8388608   (w1t[e][h][c] = W1[e][c][h])
//   wg1t [128][256] bf16 @ 9437184      (wg1t[h][c] = Wg1[c][h])
//   w2t  [256][2048] bf16 @ 9502720     (w2t[d][e*256+h] = W2[e][h][d])
//   g    [16384][8] f32 @ 10584064

typedef unsigned short USH;
typedef float f32x4 __attribute__((ext_vector_type(4)));
typedef __bf16 bf16x8 __attribute__((ext_vector_type(8)));

#define AS1 __attribute__((address_space(1)))
#define AS3 __attribute__((address_space(3)))

__device__ __forceinline__ USH f2bf(float f) {
  unsigned int u = __float_as_uint(f);
  u += 0x7fffu + ((u >> 16) & 1u);   // RNE
  return (USH)(u >> 16);
}

__device__ __forceinline__ void gl2lds16(const void* g, void* l) {
  __builtin_amdgcn_global_load_lds((AS1 const void*)g, (AS3 void*)l, 16, 0, 0);
}

// counted-vmcnt chunk sync: leave the in-flight next-chunk stage (4 loads)
// pending; drain LDS ops so ds_writes are visible and frag reads are done.
// NO sched_barrier here (m141) -- compiler stays free to schedule.
#define CHUNK_SYNC() do { \
  asm volatile("s_waitcnt vmcnt(4) lgkmcnt(0)" ::: "memory"); \
  __builtin_amdgcn_s_barrier(); } while (0)

// ---------------- prep ----------------

__global__ __launch_bounds__(256) void k_prep(
    const float* __restrict__ x,
    const float* __restrict__ Wg1,
    const float* __restrict__ W1,
    const float* __restrict__ W2,
    USH* __restrict__ xb, USH* __restrict__ wg1t,
    USH* __restrict__ w1t, USH* __restrict__ w2t) {
  __shared__ float T[64][65];
  int b = blockIdx.x, tid = threadIdx.x;

  if (b < 2048) {               // xb: flat coalesced cast
    size_t i8 = ((size_t)b * 256 + tid) * 8;
    float4 a = *(const float4*)(x + i8);
    float4 c = *(const float4*)(x + i8 + 4);
    USH v[8];
    v[0] = f2bf(a.x); v[1] = f2bf(a.y); v[2] = f2bf(a.z); v[3] = f2bf(a.w);
    v[4] = f2bf(c.x); v[5] = f2bf(c.y); v[6] = f2bf(c.z); v[7] = f2bf(c.w);
    *(uint4*)(xb + i8) = *(const uint4*)v;
  } else if (b < 2176) {        // w1t[e][h][c] = W1[e][c][h]
    int bp = b - 2048;
    int e = bp >> 4, tl = bp & 15;
    int c0 = (tl >> 2) * 64, h0 = (tl & 3) * 64;
    const float* src = W1 + (size_t)e * 65536;
#pragma unroll
    for (int p = 0; p < 4; ++p) {
      int r = p * 16 + (tid >> 4), d4 = (tid & 15) * 4;
      float4 v = *(const float4*)(src + (size_t)(c0 + r) * 256 + h0 + d4);
      T[r][d4] = v.x; T[r][d4 + 1] = v.y; T[r][d4 + 2] = v.z; T[r][d4 + 3] = v.w;
    }
    __syncthreads();
#pragma unroll
    for (int p = 0; p < 4; ++p) {
      int hr = p * 16 + (tid >> 4), c4 = (tid & 15) * 4;
      USH w[4];
#pragma unroll
      for (int j = 0; j < 4; ++j) w[j] = f2bf(T[c4 + j][hr]);
      *(uint2*)(w1t + (size_t)e * 65536 + (size_t)(h0 + hr) * 256 + c0 + c4) = *(const uint2*)w;
    }
  } else if (b < 2184) {        // wg1t[h][c] = Wg1[c][h]
    int bp = b - 2176;
    int c0 = (bp >> 1) * 64, h0 = (bp & 1) * 64;
#pragma unroll
    for (int p = 0; p < 4; ++p) {
      int r = p * 16 + (tid >> 4), d4 = (tid & 15) * 4;
      float4 v = *(const float4*)(Wg1 + (size_t)(c0 + r) * 128 + h0 + d4);
      T[r][d4] = v.x; T[r][d4 + 1] = v.y; T[r][d4 + 2] = v.z; T[r][d4 + 3] = v.w;
    }
    __syncthreads();
#pragma unroll
    for (int p = 0; p < 4; ++p) {
      int hr = p * 16 + (tid >> 4), c4 = (tid & 15) * 4;
      USH w[4];
#pragma unroll
      for (int j = 0; j < 4; ++j) w[j] = f2bf(T[c4 + j][hr]);
      *(uint2*)(wg1t + (size_t)(h0 + hr) * 256 + c0 + c4) = *(const uint2*)w;
    }
  } else {                      // w2t[d][e*256+h] = W2[e][h][d]
    int bp = b - 2184;
    int e = bp >> 4, tl = bp & 15;
    int h0 = (tl >> 2) * 64, d0 = (tl & 3) * 64;
    const float* src = W2 + (size_t)e * 65536;
#pragma unroll
    for (int p = 0; p < 4; ++p) {
      int r = p * 16 + (tid >> 4), d4 = (tid & 15) * 4;
      float4 v = *(const float4*)(src + (size_t)(h0 + r) * 256 + d0 + d4);
      T[r][d4] = v.x; T[r][d4 + 1] = v.y; T[r][d4 + 2] = v.z; T[r][d4 + 3] = v.w;
    }
    __syncthreads();
#pragma unroll
    for (int p = 0; p < 4; ++p) {
      int dr = p * 16 + (tid >> 4), h4 = (tid & 15) * 4;
      USH w[4];
#pragma unroll
      for (int j = 0; j < 4; ++j) w[j] = f2bf(T[h4 + j][dr]);
      *(uint2*)(w2t + (size_t)(d0 + dr) * 2048 + e * 256 + h0 + h4) = *(const uint2*)w;
    }
  }
}

// ---------------- gate (512 blocks x 32 rows, BK=64, swizzled) ----------------

__global__ __launch_bounds__(256) void k_gate(const USH* __restrict__ xb,
                                              const USH* __restrict__ wg1t,
                                              const float* __restrict__ bg1,
                                              const float* __restrict__ wg2,
                                              const float* __restrict__ bg2,
                                              float* __restrict__ g) {
  __shared__ __align__(16) USH As[32 * 64];
  __shared__ __align__(16) USH Bs[128 * 64];
  __shared__ float hg[32 * 129];
  __shared__ float bg1s[128];
  __shared__ float w2s[128 * 8];
  __shared__ float b2s[8];
  __shared__ float lg[32 * 8];

  int tid = threadIdx.x;
  int wave = tid >> 6, lane = tid & 63;
  int quad = lane >> 4, l16 = lane & 15;
  int sw = l16 & 7;
  int wr = wave >> 1, wc = wave & 1;
  int rowBase = blockIdx.x * 32;

  for (int t = tid; t < 1024; t += 256) w2s[t] = wg2[t];
  if (tid < 8) b2s[tid] = bg2[tid];
  if (tid < 128) bg1s[tid] = bg1[tid];

  f32x4 acc[4] = {};
  for (int kt = 0; kt < 4; ++kt) {
    int kb = kt * 64;
    {
      int r = tid >> 3, c8 = (tid & 7) ^ (r & 7);
      gl2lds16(xb + (size_t)(rowBase + r) * 256 + kb + c8 * 8, As + (size_t)tid * 8);
    }
#pragma unroll
    for (int c = 0; c < 4; ++c) {
      int i = c * 256 + tid;
      int r = i >> 3, c8 = (i & 7) ^ (r & 7);
      gl2lds16(wg1t + (size_t)r * 256 + kb + c8 * 8, Bs + (size_t)i * 8);
    }
    __syncthreads();
#pragma unroll
    for (int kkc = 0; kkc < 8; kkc += 4) {
      bf16x8 av = *(const bf16x8*)(As + (wr * 16 + l16) * 64 + (((kkc + quad) ^ sw) * 8));
#pragma unroll
      for (int j = 0; j < 4; ++j) {
        bf16x8 bv = *(const bf16x8*)(Bs + (wc * 64 + j * 16 + l16) * 64 + (((kkc + quad) ^ sw) * 8));
        acc[j] = __builtin_amdgcn_mfma_f32_16x16x32_bf16(av, bv, acc[j], 0, 0, 0);
      }
    }
    __syncthreads();
  }

#pragma unroll
  for (int j = 0; j < 4; ++j)
#pragma unroll
    for (int r = 0; r < 4; ++r) {
      int row = wr * 16 + quad * 4 + r;
      int col = wc * 64 + j * 16 + l16;
      hg[row * 129 + col] = fmaxf(acc[j][r] + bg1s[col], 0.0f);
    }
  __syncthreads();

  {
    int row = tid >> 3, p = tid & 7;
    float s = b2s[p];
    for (int k = 0; k < 128; ++k) s += hg[row * 129 + k] * w2s[k * 8 + p];
    lg[row * 8 + p] = s;
  }
  __syncthreads();

  if (tid < 32) {
    float l[8];
    float m = -1e30f;
#pragma unroll
    for (int e = 0; e < 8; ++e) { l[e] = lg[tid * 8 + e]; m = fmaxf(m, l[e]); }
    float s = 0.0f;
#pragma unroll
    for (int e = 0; e < 8; ++e) { l[e] = expf(l[e] - m); s += l[e]; }
    float inv = 1.0f / s;
    size_t grow = rowBase + tid;
#pragma unroll
    for (int e = 0; e < 8; ++e) g[grow * 8 + e] = l[e] * inv;
  }
}

// ---------------- fused experts (256 blocks x 64 rows, 512 thr) --------------

__global__ __launch_bounds__(512) void k_moe(const USH* __restrict__ xb,
                                             const USH* __restrict__ w1t,
                                             const USH* __restrict__ w2t,
                                             const float* __restrict__ b1,
                                             const float* __restrict__ b2,
                                             const float* __restrict__ g,
                                             float* __restrict__ out) {
  __shared__ __align__(16) USH Ws[3][256 * 64];   // 96KB weight triple buffer;
                                                  // Ws[2] holds the x tile at init
  __shared__ __align__(16) USH Hs[64 * 256];      // 32KB, swizzled
  __shared__ float b1s[2048];
  __shared__ float b2s[2048];
  __shared__ float gs[512];                       // gs[n*8+e]

  int tid = threadIdx.x;
  int wave = tid >> 6, lane = tid & 63;
  int quad = lane >> 4, l16 = lane & 15;
  int sw = l16 & 7;
  int rowBase = blockIdx.x * 64;

  // ---- prologue: x tile (64x256, swizzled) into Ws[2]; biases/gates to LDS
#pragma unroll
  for (int it = 0; it < 4; ++it) {
    int i = it * 512 + tid;
    int kt = i >> 9, rem = i & 511;
    int r = rem >> 3, slot = rem & 7;
    int c8 = slot ^ (r & 7);
    gl2lds16(xb + (size_t)(rowBase + r) * 256 + kt * 64 + c8 * 8, &Ws[2][0] + (size_t)i * 8);
  }
#pragma unroll
  for (int t = 0; t < 4; ++t) {
    b1s[t * 512 + tid] = b1[t * 512 + tid];
    b2s[t * 512 + tid] = b2[t * 512 + tid];
  }
  gs[tid] = g[(size_t)rowBase * 8 + tid];

  // drain everything once; after this, in-loop vmcnt == outstanding STAGEs only
  asm volatile("s_waitcnt vmcnt(0) lgkmcnt(0)" ::: "memory");
  __builtin_amdgcn_s_barrier();

  // chunk src in [0,64): e=src>>3; src&4: 0 = W1 c-chunk, 1 = W2 h-chunk
  auto STAGE = [&](int src, int bf) {
    int e = src >> 3;
    int cbo = (src & 3) * 64;
    const USH* sp;
    size_t stride;
    if (src & 4) { sp = w2t + e * 256 + cbo;           stride = 2048; }
    else         { sp = w1t + (size_t)e * 65536 + cbo; stride = 256;  }
    USH* dst = &Ws[bf][0];
#pragma unroll
    for (int it = 0; it < 4; ++it) {
      int i = it * 512 + tid;
      int r = i >> 3, slot = i & 7;
      int c8 = slot ^ (r & 7);
      gl2lds16(sp + (size_t)r * stride + c8 * 8, dst + (size_t)i * 8);
    }
  };

  int wh = wave >> 1, wn = wave & 1;    // phase-1: wave = 64h x 32n
  int wn2 = wave >> 2, wd = wave & 3;   // phase-2: wave = 32n x 64d

  STAGE(0, 0);
  STAGE(1, 1);

  // x fragments -> 64 VGPRs (reused by all 8 experts); reads drain at the
  // first CHUNK_SYNC's lgkmcnt(0), before Ws[2] is restaged (chunk T=2).
  bf16x8 xr[4][2][2];
#pragma unroll
  for (int kt = 0; kt < 4; ++kt)
#pragma unroll
    for (int c = 0; c < 2; ++c)
#pragma unroll
      for (int j = 0; j < 2; ++j)
        xr[kt][c][j] = *(const bf16x8*)(&Ws[2][0] + kt * 4096 +
                         (wn * 32 + j * 16 + l16) * 64 + (((c * 4 + quad) ^ sw) * 8));

  f32x4 oacc[2][4] = {};

#pragma unroll 1
  for (int e = 0; e < 8; ++e) {
    f32x4 hacc[4][2] = {};

    // phase 1: H^T[h,n] = sum_c W1[c,h] * x[n,c]
#pragma unroll
    for (int kt = 0; kt < 4; ++kt) {
      int T = e * 8 + kt;
      CHUNK_SYNC();                       // Ws[T%3] ready; T+1 still in flight
      STAGE((T + 2) & 63, (T + 2) % 3);   // &63: tail restages 0/1 (unread dummy)
      const USH* W = &Ws[T % 3][0];
#pragma unroll
      for (int c = 0; c < 2; ++c) {
        int cs = ((c * 4 + quad) ^ sw) * 8;
        bf16x8 av[4];
#pragma unroll
        for (int i = 0; i < 4; ++i)
          av[i] = *(const bf16x8*)(W + (wh * 64 + i * 16 + l16) * 64 + cs);
#pragma unroll
        for (int i = 0; i < 4; ++i)
#pragma unroll
          for (int j = 0; j < 2; ++j)
            hacc[i][j] = __builtin_amdgcn_mfma_f32_16x16x32_bf16(av[i], xr[kt][c][j], hacc[i][j], 0, 0, 0);
      }
    }

    // epilogue: Hs[n][h] = bf16(relu(hacc+b1)*g[n,e]); C[h,n]: 4 consecutive h
    // per reg quad -> ds_write_b64, directly in phase-2 A-frag layout.
#pragma unroll
    for (int i = 0; i < 4; ++i) {
      int c8 = i * 2 + (quad >> 1);
      int hb = wh * 64 + i * 16 + quad * 4;
#pragma unroll
      for (int j = 0; j < 2; ++j) {
        int n = wn * 32 + j * 16 + l16;
        float gg = gs[n * 8 + e];
        USH w4[4];
#pragma unroll
        for (int r = 0; r < 4; ++r)
          w4[r] = f2bf(fmaxf(hacc[i][j][r] + b1s[e * 256 + hb + r], 0.0f) * gg);
        int off = n * 256 + wh * 64 + (c8 ^ (n & 7)) * 8 + (quad & 1) * 4;
        *(uint2*)(Hs + off) = *(const uint2*)w4;
      }
    }

    // phase 2: out[n,d] += sum_h Hs[n,h] * W2[h,d]
#pragma unroll
    for (int ht = 0; ht < 4; ++ht) {
      int T = e * 8 + 4 + ht;
      CHUNK_SYNC();                       // Hs writes visible; Ws[T%3] ready
      STAGE((T + 2) & 63, (T + 2) % 3);
      const USH* W = &Ws[T % 3][0];
#pragma unroll
      for (int c = 0; c < 2; ++c) {
        int cs = ((c * 4 + quad) ^ sw) * 8;
        bf16x8 av[2], bv[4];
#pragma unroll
        for (int i = 0; i < 2; ++i)
          av[i] = *(const bf16x8*)(Hs + (wn2 * 32 + i * 16 + l16) * 256 + ht * 64 + cs);
#pragma unroll
        for (int j = 0; j < 4; ++j)
          bv[j] = *(const bf16x8*)(W + (wd * 64 + j * 16 + l16) * 64 + cs);
#pragma unroll
        for (int i = 0; i < 2; ++i)
#pragma unroll
          for (int j = 0; j < 4; ++j)
            oacc[i][j] = __builtin_amdgcn_mfma_f32_16x16x32_bf16(av[i], bv[j], oacc[i][j], 0, 0, 0);
      }
    }
  }

  // drain tail dummy stages before exit path
  asm volatile("s_waitcnt vmcnt(0)" ::: "memory");

  // final epilogue: out = oacc + sum_e g[n,e]*b2[e,d]  (exact f32 bias)
#pragma unroll
  for (int i = 0; i < 2; ++i)
#pragma unroll
    for (int r = 0; r < 4; ++r) {
      int n = wn2 * 32 + i * 16 + quad * 4 + r;
      const float* gr = gs + n * 8;
      size_t grow = (size_t)(rowBase + n) * 256;
#pragma unroll
      for (int j = 0; j < 4; ++j) {
        int d = wd * 64 + j * 16 + l16;
        float bias = 0.0f;
#pragma unroll
        for (int ee = 0; ee < 8; ++ee) bias += gr[ee] * b2s[ee * 256 + d];
        out[grow + d] = oacc[i][j][r] + bias;
      }
    }
}

// ---------------- launch ----------------

extern "C" void kernel_launch(void* const* d_in, const int* in_sizes, int n_in,
                              void* d_out, int out_size, void* d_ws, size_t ws_size,
                              hipStream_t stream) {
  const float* x   = (const float*)d_in[0];
  const float* Wg1 = (const float*)d_in[1];
  const float* bg1 = (const float*)d_in[2];
  const float* Wg2 = (const float*)d_in[3];
  const float* bg2 = (const float*)d_in[4];
  const float* W1  = (const float*)d_in[5];
  const float* b1  = (const float*)d_in[6];
  const float* W2  = (const float*)d_in[7];
  const float* b2  = (const float*)d_in[8];
  float* out = (float*)d_out;

  char* ws = (char*)d_ws;
  USH*   xb   = (USH*)(ws);
  USH*   w1t  = (USH*)(ws + 8388608);
  USH*   wg1t = (USH*)(ws + 9437184);
  USH*   w2t  = (USH*)(ws + 9502720);
  float* g    = (float*)(ws + 10584064);

  hipLaunchKernelGGL(k_prep, dim3(2312), dim3(256), 0, stream,
                     x, Wg1, W1, W2, xb, wg1t, w1t, w2t);
  hipLaunchKernelGGL(k_gate, dim3(512), dim3(256), 0, stream,
                     xb, wg1t, bg1, Wg2, bg2, g);
  hipLaunchKernelGGL(k_moe, dim3(256), dim3(512), 0, stream,
                     xb, w1t, w2t, b1, b2, g, out);
}

// Round 4
// 145.767 us; speedup vs baseline: 1.1277x; 1.1101x over previous
//
#include <hip/hip_runtime.h>

// MoE dense: N=16384, D=256, E=8, H=256 (expert hidden = D).
// R12: weights NEVER touch LDS. R9-R11 all plateaued 64-74us / MfmaUtil<22%:
// the LDS weight round-trip (stage 32KB + read 64-96KB per chunk) + 64
// lockstep barriers at 2 waves/SIMD was the wall. k_prep now writes W1/W2 in
// MFMA-fragment-major order (w1f/w2f: 1KB fragment = [lane][16B], so a wave's
// av/bv loads are single coalesced global_load_dwordx4 from L2). k_moe:
//  - x in 128 VGPRs (32 bf16x8 frags), loaded once, reused by all 8 experts
//  - phase 1 (H^T[h,n] = W1^T x^T): pure register GEMM, weights stream L2->VGPR,
//    wave owns 32 h -> zero intra-block duplication of weight loads
//  - Hs (32KB, XOR-swizzled) is the ONLY LDS tile: transpose handoff of H
//  - phase 2: Hs A-frags + W2 fragment stream, wave owns 32 d
//  - 2 barriers per expert (16 total) instead of 64
// LDS 51KB; VGPR ~240 -> 1 block/CU, 8 waves. L2 weight traffic 512MB ~ 15us.
// Workspace (offsets unchanged):
//   xb   [16384][256] bf16 @ 0
//   w1f  fragment-major W1 @ 8388608   (1MB)
//   wg1t [128][256] bf16 @ 9437184
//   w2f  fragment-major W2 @ 9502720   (1MB)
//   g    [16384][8] f32 @ 10584064

typedef unsigned short USH;
typedef float f32x4 __attribute__((ext_vector_type(4)));
typedef __bf16 bf16x8 __attribute__((ext_vector_type(8)));

#define AS1 __attribute__((address_space(1)))
#define AS3 __attribute__((address_space(3)))

__device__ __forceinline__ USH f2bf(float f) {
  unsigned int u = __float_as_uint(f);
  u += 0x7fffu + ((u >> 16) & 1u);   // RNE
  return (USH)(u >> 16);
}

__device__ __forceinline__ void gl2lds16(const void* g, void* l) {
  __builtin_amdgcn_global_load_lds((AS1 const void*)g, (AS3 void*)l, 16, 0, 0);
}

// ---------------- prep ----------------
// w1f fragment layout: for (e, kt=c>>6, t=h>>4, ch=(c>>5)&1):
//   idx = ((e*64 + kt*16 + t)*2 + ch)*512 + (q*16 + (h&15))*8 + (c&7)
//   where q=(c>>3)&3. Fragment block = 512 USH = [lane=q*16+l16][8 c-elems],
//   value = W1[e][c][h]. w2f identical with (h<->role of c, d<->role of h):
//   value = W2[e][h][d], kt=h>>6, t=d>>4, ch=(h>>5)&1, q=(h>>3)&3, u=h&7.

__global__ __launch_bounds__(256) void k_prep(
    const float* __restrict__ x,
    const float* __restrict__ Wg1,
    const float* __restrict__ W1,
    const float* __restrict__ W2,
    USH* __restrict__ xb, USH* __restrict__ wg1t,
    USH* __restrict__ w1f, USH* __restrict__ w2f) {
  __shared__ float T[64][65];
  int b = blockIdx.x, tid = threadIdx.x;

  if (b < 2048) {               // xb: flat coalesced cast
    size_t i8 = ((size_t)b * 256 + tid) * 8;
    float4 a = *(const float4*)(x + i8);
    float4 c = *(const float4*)(x + i8 + 4);
    USH v[8];
    v[0] = f2bf(a.x); v[1] = f2bf(a.y); v[2] = f2bf(a.z); v[3] = f2bf(a.w);
    v[4] = f2bf(c.x); v[5] = f2bf(c.y); v[6] = f2bf(c.z); v[7] = f2bf(c.w);
    *(uint4*)(xb + i8) = *(const uint4*)v;
  } else if (b < 2176) {        // w1f: fragment-major W1
    int bp = b - 2048;
    int e = bp >> 4, tl = bp & 15;
    int c0 = (tl >> 2) * 64, h0 = (tl & 3) * 64;
    const float* src = W1 + (size_t)e * 65536;
#pragma unroll
    for (int p = 0; p < 4; ++p) {
      int r = p * 16 + (tid >> 4), d4 = (tid & 15) * 4;
      float4 v = *(const float4*)(src + (size_t)(c0 + r) * 256 + h0 + d4);
      T[r][d4] = v.x; T[r][d4 + 1] = v.y; T[r][d4 + 2] = v.z; T[r][d4 + 3] = v.w;
    }
    __syncthreads();
#pragma unroll
    for (int p = 0; p < 4; ++p) {
      int hr = p * 16 + (tid >> 4), c4 = (tid & 15) * 4;
      USH w[4];
#pragma unroll
      for (int j = 0; j < 4; ++j) w[j] = f2bf(T[c4 + j][hr]);   // = W1[e][c0+c4+j][h0+hr]
      int h = h0 + hr;
      int t = h >> 4, lh = h & 15;
      int kt = c0 >> 6, ch = c4 >> 5, q = (c4 >> 3) & 3, u0 = c4 & 7;
      size_t idx = ((size_t)((e * 64 + kt * 16 + t) * 2 + ch)) * 512 + (q * 16 + lh) * 8 + u0;
      *(uint2*)(w1f + idx) = *(const uint2*)w;
    }
  } else if (b < 2184) {        // wg1t[h][c] = Wg1[c][h]  (gate, unchanged)
    int bp = b - 2176;
    int c0 = (bp >> 1) * 64, h0 = (bp & 1) * 64;
#pragma unroll
    for (int p = 0; p < 4; ++p) {
      int r = p * 16 + (tid >> 4), d4 = (tid & 15) * 4;
      float4 v = *(const float4*)(Wg1 + (size_t)(c0 + r) * 128 + h0 + d4);
      T[r][d4] = v.x; T[r][d4 + 1] = v.y; T[r][d4 + 2] = v.z; T[r][d4 + 3] = v.w;
    }
    __syncthreads();
#pragma unroll
    for (int p = 0; p < 4; ++p) {
      int hr = p * 16 + (tid >> 4), c4 = (tid & 15) * 4;
      USH w[4];
#pragma unroll
      for (int j = 0; j < 4; ++j) w[j] = f2bf(T[c4 + j][hr]);
      *(uint2*)(wg1t + (size_t)(h0 + hr) * 256 + c0 + c4) = *(const uint2*)w;
    }
  } else {                      // w2f: fragment-major W2
    int bp = b - 2184;
    int e = bp >> 4, tl = bp & 15;
    int h0 = (tl >> 2) * 64, d0 = (tl & 3) * 64;
    const float* src = W2 + (size_t)e * 65536;
#pragma unroll
    for (int p = 0; p < 4; ++p) {
      int r = p * 16 + (tid >> 4), d4 = (tid & 15) * 4;
      float4 v = *(const float4*)(src + (size_t)(h0 + r) * 256 + d0 + d4);
      T[r][d4] = v.x; T[r][d4 + 1] = v.y; T[r][d4 + 2] = v.z; T[r][d4 + 3] = v.w;
    }
    __syncthreads();
#pragma unroll
    for (int p = 0; p < 4; ++p) {
      int dr = p * 16 + (tid >> 4), h4 = (tid & 15) * 4;
      USH w[4];
#pragma unroll
      for (int j = 0; j < 4; ++j) w[j] = f2bf(T[h4 + j][dr]);   // = W2[e][h0+h4+j][d0+dr]
      int d = d0 + dr;
      int t = d >> 4, ld = d & 15;
      int ht = h0 >> 6, ch = h4 >> 5, q = (h4 >> 3) & 3, u0 = h4 & 7;
      size_t idx = ((size_t)((e * 64 + ht * 16 + t) * 2 + ch)) * 512 + (q * 16 + ld) * 8 + u0;
      *(uint2*)(w2f + idx) = *(const uint2*)w;
    }
  }
}

// ---------------- gate (512 blocks x 32 rows, BK=64, swizzled) ----------------

__global__ __launch_bounds__(256) void k_gate(const USH* __restrict__ xb,
                                              const USH* __restrict__ wg1t,
                                              const float* __restrict__ bg1,
                                              const float* __restrict__ wg2,
                                              const float* __restrict__ bg2,
                                              float* __restrict__ g) {
  __shared__ __align__(16) USH As[32 * 64];
  __shared__ __align__(16) USH Bs[128 * 64];
  __shared__ float hg[32 * 129];
  __shared__ float bg1s[128];
  __shared__ float w2s[128 * 8];
  __shared__ float b2s[8];
  __shared__ float lg[32 * 8];

  int tid = threadIdx.x;
  int wave = tid >> 6, lane = tid & 63;
  int quad = lane >> 4, l16 = lane & 15;
  int sw = l16 & 7;
  int wr = wave >> 1, wc = wave & 1;
  int rowBase = blockIdx.x * 32;

  for (int t = tid; t < 1024; t += 256) w2s[t] = wg2[t];
  if (tid < 8) b2s[tid] = bg2[tid];
  if (tid < 128) bg1s[tid] = bg1[tid];

  f32x4 acc[4] = {};
  for (int kt = 0; kt < 4; ++kt) {
    int kb = kt * 64;
    {
      int r = tid >> 3, c8 = (tid & 7) ^ (r & 7);
      gl2lds16(xb + (size_t)(rowBase + r) * 256 + kb + c8 * 8, As + (size_t)tid * 8);
    }
#pragma unroll
    for (int c = 0; c < 4; ++c) {
      int i = c * 256 + tid;
      int r = i >> 3, c8 = (i & 7) ^ (r & 7);
      gl2lds16(wg1t + (size_t)r * 256 + kb + c8 * 8, Bs + (size_t)i * 8);
    }
    __syncthreads();
#pragma unroll
    for (int kkc = 0; kkc < 8; kkc += 4) {
      bf16x8 av = *(const bf16x8*)(As + (wr * 16 + l16) * 64 + (((kkc + quad) ^ sw) * 8));
#pragma unroll
      for (int j = 0; j < 4; ++j) {
        bf16x8 bv = *(const bf16x8*)(Bs + (wc * 64 + j * 16 + l16) * 64 + (((kkc + quad) ^ sw) * 8));
        acc[j] = __builtin_amdgcn_mfma_f32_16x16x32_bf16(av, bv, acc[j], 0, 0, 0);
      }
    }
    __syncthreads();
  }

#pragma unroll
  for (int j = 0; j < 4; ++j)
#pragma unroll
    for (int r = 0; r < 4; ++r) {
      int row = wr * 16 + quad * 4 + r;
      int col = wc * 64 + j * 16 + l16;
      hg[row * 129 + col] = fmaxf(acc[j][r] + bg1s[col], 0.0f);
    }
  __syncthreads();

  {
    int row = tid >> 3, p = tid & 7;
    float s = b2s[p];
    for (int k = 0; k < 128; ++k) s += hg[row * 129 + k] * w2s[k * 8 + p];
    lg[row * 8 + p] = s;
  }
  __syncthreads();

  if (tid < 32) {
    float l[8];
    float m = -1e30f;
#pragma unroll
    for (int e = 0; e < 8; ++e) { l[e] = lg[tid * 8 + e]; m = fmaxf(m, l[e]); }
    float s = 0.0f;
#pragma unroll
    for (int e = 0; e < 8; ++e) { l[e] = expf(l[e] - m); s += l[e]; }
    float inv = 1.0f / s;
    size_t grow = rowBase + tid;
#pragma unroll
    for (int e = 0; e < 8; ++e) g[grow * 8 + e] = l[e] * inv;
  }
}

// ---------------- fused experts (256 blocks x 64 rows, 512 thr) --------------

__global__ __launch_bounds__(512, 2) void k_moe(const USH* __restrict__ xb,
                                                const USH* __restrict__ w1f,
                                                const USH* __restrict__ w2f,
                                                const float* __restrict__ b1,
                                                const float* __restrict__ b2,
                                                const float* __restrict__ g,
                                                float* __restrict__ out) {
  __shared__ __align__(16) USH Hs[64 * 256];   // 32KB, XOR-swizzled
  __shared__ float b1s[2048];
  __shared__ float b2s[2048];
  __shared__ float gs[512];                    // gs[n*8+e]

  int tid = threadIdx.x;
  int wave = tid >> 6, lane = tid & 63;
  int quad = lane >> 4, l16 = lane & 15;
  int sw = l16 & 7;
  int rowBase = blockIdx.x * 64;

#pragma unroll
  for (int t = 0; t < 4; ++t) {
    b1s[t * 512 + tid] = b1[t * 512 + tid];
    b2s[t * 512 + tid] = b2[t * 512 + tid];
  }
  gs[tid] = g[(size_t)rowBase * 8 + tid];

  // x fragments -> 128 VGPRs, loaded once, reused by all 8 experts.
  // xr[kt][c][j] lane(quad,l16) = x[n=j*16+l16][kt*64 + c*32 + quad*8 ..+8]
  bf16x8 xr[4][2][4];
#pragma unroll
  for (int kt = 0; kt < 4; ++kt)
#pragma unroll
    for (int c = 0; c < 2; ++c)
#pragma unroll
      for (int j = 0; j < 4; ++j)
        xr[kt][c][j] = *(const bf16x8*)(xb + (size_t)(rowBase + j * 16 + l16) * 256 +
                                        kt * 64 + c * 32 + quad * 8);

  __syncthreads();   // gs/b1s/b2s visible

  f32x4 oacc[4][2] = {};

#pragma unroll 1
  for (int e = 0; e < 8; ++e) {
    const USH* W1e = w1f + (size_t)e * 65536;
    const USH* W2e = w2f + (size_t)e * 65536;
    f32x4 hacc[2][4] = {};

    // phase 1: H^T[h,n] = sum_c W1[c,h]*x[n,c]; wave owns h = wave*32..+31.
    // Weights stream L2 -> VGPR via coalesced fragment loads (no LDS).
#pragma unroll
    for (int kt = 0; kt < 4; ++kt)
#pragma unroll
      for (int c = 0; c < 2; ++c) {
        bf16x8 av[2];
#pragma unroll
        for (int i = 0; i < 2; ++i)
          av[i] = *(const bf16x8*)(W1e + (size_t)((kt * 16 + wave * 2 + i) * 2 + c) * 512 + lane * 8);
#pragma unroll
        for (int i = 0; i < 2; ++i)
#pragma unroll
          for (int j = 0; j < 4; ++j)
            hacc[i][j] = __builtin_amdgcn_mfma_f32_16x16x32_bf16(av[i], xr[kt][c][j], hacc[i][j], 0, 0, 0);
      }

    // epilogue 1: Hs[n][h] = bf16(relu(hacc+b1)*g[n,e]); 4 consecutive h per
    // reg quad -> uint2 write, XOR-swizzled to match phase-2 A-frag reads.
#pragma unroll
    for (int i = 0; i < 2; ++i) {
      int slot = (wave & 1) * 4 + i * 2 + (quad >> 1);   // (h>>3)&7
      int hb = wave * 32 + i * 16 + quad * 4;
#pragma unroll
      for (int j = 0; j < 4; ++j) {
        int n = j * 16 + l16;
        float gg = gs[n * 8 + e];
        USH w4[4];
#pragma unroll
        for (int r = 0; r < 4; ++r)
          w4[r] = f2bf(fmaxf(hacc[i][j][r] + b1s[e * 256 + hb + r], 0.0f) * gg);
        int off = n * 256 + (wave >> 1) * 64 + ((slot ^ (n & 7)) * 8) + (quad & 1) * 4;
        *(uint2*)(Hs + off) = *(const uint2*)w4;
      }
    }
    __syncthreads();

    // phase 2: out[n,d] += sum_h Hs[n,h]*W2[h,d]; wave owns d = wave*32..+31.
#pragma unroll
    for (int ht = 0; ht < 4; ++ht)
#pragma unroll
      for (int c = 0; c < 2; ++c) {
        bf16x8 bv[2], av[4];
#pragma unroll
        for (int j = 0; j < 2; ++j)
          bv[j] = *(const bf16x8*)(W2e + (size_t)((ht * 16 + wave * 2 + j) * 2 + c) * 512 + lane * 8);
#pragma unroll
        for (int i = 0; i < 4; ++i)
          av[i] = *(const bf16x8*)(Hs + (i * 16 + l16) * 256 + ht * 64 + (((c * 4 + quad) ^ sw) * 8));
#pragma unroll
        for (int i = 0; i < 4; ++i)
#pragma unroll
          for (int j = 0; j < 2; ++j)
            oacc[i][j] = __builtin_amdgcn_mfma_f32_16x16x32_bf16(av[i], bv[j], oacc[i][j], 0, 0, 0);
      }
    __syncthreads();   // Hs reads done before next expert's epilogue-1 writes
  }

  // final epilogue: out = oacc + sum_e g[n,e]*b2[e,d]  (exact f32 bias)
#pragma unroll
  for (int i = 0; i < 4; ++i)
#pragma unroll
    for (int r = 0; r < 4; ++r) {
      int n = i * 16 + quad * 4 + r;
      const float* gr = gs + n * 8;
      size_t grow = (size_t)(rowBase + n) * 256;
#pragma unroll
      for (int j = 0; j < 2; ++j) {
        int d = wave * 32 + j * 16 + l16;
        float bias = 0.0f;
#pragma unroll
        for (int ee = 0; ee < 8; ++ee) bias += gr[ee] * b2s[ee * 256 + d];
        out[grow + d] = oacc[i][j][r] + bias;
      }
    }
}

// ---------------- launch ----------------

extern "C" void kernel_launch(void* const* d_in, const int* in_sizes, int n_in,
                              void* d_out, int out_size, void* d_ws, size_t ws_size,
                              hipStream_t stream) {
  const float* x   = (const float*)d_in[0];
  const float* Wg1 = (const float*)d_in[1];
  const float* bg1 = (const float*)d_in[2];
  const float* Wg2 = (const float*)d_in[3];
  const float* bg2 = (const float*)d_in[4];
  const float* W1  = (const float*)d_in[5];
  const float* b1  = (const float*)d_in[6];
  const float* W2  = (const float*)d_in[7];
  const float* b2  = (const float*)d_in[8];
  float* out = (float*)d_out;

  char* ws = (char*)d_ws;
  USH*   xb  = (USH*)(ws);
  USH*   w1f = (USH*)(ws + 8388608);
  USH*   wg1t = (USH*)(ws + 9437184);
  USH*   w2f = (USH*)(ws + 9502720);
  float* g   = (float*)(ws + 10584064);

  hipLaunchKernelGGL(k_prep, dim3(2312), dim3(256), 0, stream,
                     x, Wg1, W1, W2, xb, wg1t, w1f, w2f);
  hipLaunchKernelGGL(k_gate, dim3(512), dim3(256), 0, stream,
                     xb, wg1t, bg1, Wg2, bg2, g);
  hipLaunchKernelGGL(k_moe, dim3(256), dim3(512), 0, stream,
                     xb, w1f, w2f, b1, b2, g, out);
}

// Round 5
// 130.624 us; speedup vs baseline: 1.2584x; 1.1159x over previous
//
#include <hip/hip_runtime.h>

// MoE dense: N=16384, D=256, E=8, H=256 (expert hidden = D).
// R13: pipeline the R12 structure. R12 (56us, MfmaUtil 23%) exposed L2 weight
// latency per (kt,c) step at 2 waves/SIMD and drained prefetches at 16
// __syncthreads (vmcnt(0)). Changes:
//  - x tile back in LDS (xs, 32KB, proven R11 layout) -> register budget
//    closes at ~190/wave (R12 demanded ~320 vs the 256 cap; VGPR_Count=124
//    proved the compiler didn't keep xr resident as planned).
//  - rotating half-phase weight prefetch wra[8]/wrb[8]: W2(e) issued mid
//    phase-1, W1(e+1) issued mid phase-2 -> every load has ~400-600cyc of
//    MFMA+epilogue+barrier before first use.
//  - Hs double-buffered (2x32KB) -> ONE raw barrier per expert (8 total):
//    s_waitcnt lgkmcnt(0) + s_barrier, NO vmcnt drain -> prefetches live
//    across barriers.
//  - gs transposed to gse[e][n]: kills the 16-way bank conflict on epilogue
//    gate reads (R12's conflict rise 2.3M->3.1M).
// Workspace (offsets unchanged):
//   xb   [16384][256] bf16 @ 0
//   w1f  fragment-major W1 @ 8388608   (1MB)
//   wg1t [128][256] bf16 @ 9437184
//   w2f  fragment-major W2 @ 9502720   (1MB)
//   g    [16384][8] f32 @ 10584064

typedef unsigned short USH;
typedef float f32x4 __attribute__((ext_vector_type(4)));
typedef __bf16 bf16x8 __attribute__((ext_vector_type(8)));

#define AS1 __attribute__((address_space(1)))
#define AS3 __attribute__((address_space(3)))

__device__ __forceinline__ USH f2bf(float f) {
  unsigned int u = __float_as_uint(f);
  u += 0x7fffu + ((u >> 16) & 1u);   // RNE
  return (USH)(u >> 16);
}

__device__ __forceinline__ void gl2lds16(const void* g, void* l) {
  __builtin_amdgcn_global_load_lds((AS1 const void*)g, (AS3 void*)l, 16, 0, 0);
}

// ---------------- prep ----------------
// w1f fragment layout: for (e, kt=c>>6, t=h>>4, ch=(c>>5)&1):
//   idx = ((e*64 + kt*16 + t)*2 + ch)*512 + (q*16 + (h&15))*8 + (c&7)
//   where q=(c>>3)&3. Fragment block = 512 USH = [lane=q*16+l16][8 c-elems],
//   value = W1[e][c][h]. w2f identical with roles (c->h, h->d):
//   value = W2[e][h][d].

__global__ __launch_bounds__(256) void k_prep(
    const float* __restrict__ x,
    const float* __restrict__ Wg1,
    const float* __restrict__ W1,
    const float* __restrict__ W2,
    USH* __restrict__ xb, USH* __restrict__ wg1t,
    USH* __restrict__ w1f, USH* __restrict__ w2f) {
  __shared__ float T[64][65];
  int b = blockIdx.x, tid = threadIdx.x;

  if (b < 2048) {               // xb: flat coalesced cast
    size_t i8 = ((size_t)b * 256 + tid) * 8;
    float4 a = *(const float4*)(x + i8);
    float4 c = *(const float4*)(x + i8 + 4);
    USH v[8];
    v[0] = f2bf(a.x); v[1] = f2bf(a.y); v[2] = f2bf(a.z); v[3] = f2bf(a.w);
    v[4] = f2bf(c.x); v[5] = f2bf(c.y); v[6] = f2bf(c.z); v[7] = f2bf(c.w);
    *(uint4*)(xb + i8) = *(const uint4*)v;
  } else if (b < 2176) {        // w1f: fragment-major W1
    int bp = b - 2048;
    int e = bp >> 4, tl = bp & 15;
    int c0 = (tl >> 2) * 64, h0 = (tl & 3) * 64;
    const float* src = W1 + (size_t)e * 65536;
#pragma unroll
    for (int p = 0; p < 4; ++p) {
      int r = p * 16 + (tid >> 4), d4 = (tid & 15) * 4;
      float4 v = *(const float4*)(src + (size_t)(c0 + r) * 256 + h0 + d4);
      T[r][d4] = v.x; T[r][d4 + 1] = v.y; T[r][d4 + 2] = v.z; T[r][d4 + 3] = v.w;
    }
    __syncthreads();
#pragma unroll
    for (int p = 0; p < 4; ++p) {
      int hr = p * 16 + (tid >> 4), c4 = (tid & 15) * 4;
      USH w[4];
#pragma unroll
      for (int j = 0; j < 4; ++j) w[j] = f2bf(T[c4 + j][hr]);   // = W1[e][c0+c4+j][h0+hr]
      int h = h0 + hr;
      int t = h >> 4, lh = h & 15;
      int kt = c0 >> 6, ch = c4 >> 5, q = (c4 >> 3) & 3, u0 = c4 & 7;
      size_t idx = ((size_t)((e * 64 + kt * 16 + t) * 2 + ch)) * 512 + (q * 16 + lh) * 8 + u0;
      *(uint2*)(w1f + idx) = *(const uint2*)w;
    }
  } else if (b < 2184) {        // wg1t[h][c] = Wg1[c][h]  (gate, unchanged)
    int bp = b - 2176;
    int c0 = (bp >> 1) * 64, h0 = (bp & 1) * 64;
#pragma unroll
    for (int p = 0; p < 4; ++p) {
      int r = p * 16 + (tid >> 4), d4 = (tid & 15) * 4;
      float4 v = *(const float4*)(Wg1 + (size_t)(c0 + r) * 128 + h0 + d4);
      T[r][d4] = v.x; T[r][d4 + 1] = v.y; T[r][d4 + 2] = v.z; T[r][d4 + 3] = v.w;
    }
    __syncthreads();
#pragma unroll
    for (int p = 0; p < 4; ++p) {
      int hr = p * 16 + (tid >> 4), c4 = (tid & 15) * 4;
      USH w[4];
#pragma unroll
      for (int j = 0; j < 4; ++j) w[j] = f2bf(T[c4 + j][hr]);
      *(uint2*)(wg1t + (size_t)(h0 + hr) * 256 + c0 + c4) = *(const uint2*)w;
    }
  } else {                      // w2f: fragment-major W2
    int bp = b - 2184;
    int e = bp >> 4, tl = bp & 15;
    int h0 = (tl >> 2) * 64, d0 = (tl & 3) * 64;
    const float* src = W2 + (size_t)e * 65536;
#pragma unroll
    for (int p = 0; p < 4; ++p) {
      int r = p * 16 + (tid >> 4), d4 = (tid & 15) * 4;
      float4 v = *(const float4*)(src + (size_t)(h0 + r) * 256 + d0 + d4);
      T[r][d4] = v.x; T[r][d4 + 1] = v.y; T[r][d4 + 2] = v.z; T[r][d4 + 3] = v.w;
    }
    __syncthreads();
#pragma unroll
    for (int p = 0; p < 4; ++p) {
      int dr = p * 16 + (tid >> 4), h4 = (tid & 15) * 4;
      USH w[4];
#pragma unroll
      for (int j = 0; j < 4; ++j) w[j] = f2bf(T[h4 + j][dr]);   // = W2[e][h0+h4+j][d0+dr]
      int d = d0 + dr;
      int t = d >> 4, ld = d & 15;
      int ht = h0 >> 6, ch = h4 >> 5, q = (h4 >> 3) & 3, u0 = h4 & 7;
      size_t idx = ((size_t)((e * 64 + ht * 16 + t) * 2 + ch)) * 512 + (q * 16 + ld) * 8 + u0;
      *(uint2*)(w2f + idx) = *(const uint2*)w;
    }
  }
}

// ---------------- gate (512 blocks x 32 rows, BK=64, swizzled) ----------------

__global__ __launch_bounds__(256) void k_gate(const USH* __restrict__ xb,
                                              const USH* __restrict__ wg1t,
                                              const float* __restrict__ bg1,
                                              const float* __restrict__ wg2,
                                              const float* __restrict__ bg2,
                                              float* __restrict__ g) {
  __shared__ __align__(16) USH As[32 * 64];
  __shared__ __align__(16) USH Bs[128 * 64];
  __shared__ float hg[32 * 129];
  __shared__ float bg1s[128];
  __shared__ float w2s[128 * 8];
  __shared__ float b2s[8];
  __shared__ float lg[32 * 8];

  int tid = threadIdx.x;
  int wave = tid >> 6, lane = tid & 63;
  int quad = lane >> 4, l16 = lane & 15;
  int sw = l16 & 7;
  int wr = wave >> 1, wc = wave & 1;
  int rowBase = blockIdx.x * 32;

  for (int t = tid; t < 1024; t += 256) w2s[t] = wg2[t];
  if (tid < 8) b2s[tid] = bg2[tid];
  if (tid < 128) bg1s[tid] = bg1[tid];

  f32x4 acc[4] = {};
  for (int kt = 0; kt < 4; ++kt) {
    int kb = kt * 64;
    {
      int r = tid >> 3, c8 = (tid & 7) ^ (r & 7);
      gl2lds16(xb + (size_t)(rowBase + r) * 256 + kb + c8 * 8, As + (size_t)tid * 8);
    }
#pragma unroll
    for (int c = 0; c < 4; ++c) {
      int i = c * 256 + tid;
      int r = i >> 3, c8 = (i & 7) ^ (r & 7);
      gl2lds16(wg1t + (size_t)r * 256 + kb + c8 * 8, Bs + (size_t)i * 8);
    }
    __syncthreads();
#pragma unroll
    for (int kkc = 0; kkc < 8; kkc += 4) {
      bf16x8 av = *(const bf16x8*)(As + (wr * 16 + l16) * 64 + (((kkc + quad) ^ sw) * 8));
#pragma unroll
      for (int j = 0; j < 4; ++j) {
        bf16x8 bv = *(const bf16x8*)(Bs + (wc * 64 + j * 16 + l16) * 64 + (((kkc + quad) ^ sw) * 8));
        acc[j] = __builtin_amdgcn_mfma_f32_16x16x32_bf16(av, bv, acc[j], 0, 0, 0);
      }
    }
    __syncthreads();
  }

#pragma unroll
  for (int j = 0; j < 4; ++j)
#pragma unroll
    for (int r = 0; r < 4; ++r) {
      int row = wr * 16 + quad * 4 + r;
      int col = wc * 64 + j * 16 + l16;
      hg[row * 129 + col] = fmaxf(acc[j][r] + bg1s[col], 0.0f);
    }
  __syncthreads();

  {
    int row = tid >> 3, p = tid & 7;
    float s = b2s[p];
    for (int k = 0; k < 128; ++k) s += hg[row * 129 + k] * w2s[k * 8 + p];
    lg[row * 8 + p] = s;
  }
  __syncthreads();

  if (tid < 32) {
    float l[8];
    float m = -1e30f;
#pragma unroll
    for (int e = 0; e < 8; ++e) { l[e] = lg[tid * 8 + e]; m = fmaxf(m, l[e]); }
    float s = 0.0f;
#pragma unroll
    for (int e = 0; e < 8; ++e) { l[e] = expf(l[e] - m); s += l[e]; }
    float inv = 1.0f / s;
    size_t grow = rowBase + tid;
#pragma unroll
    for (int e = 0; e < 8; ++e) g[grow * 8 + e] = l[e] * inv;
  }
}

// ---------------- fused experts (256 blocks x 64 rows, 512 thr) --------------

__global__ __launch_bounds__(512) void k_moe(const USH* __restrict__ xb,
                                             const USH* __restrict__ w1f,
                                             const USH* __restrict__ w2f,
                                             const float* __restrict__ b1,
                                             const float* __restrict__ b2,
                                             const float* __restrict__ g,
                                             float* __restrict__ out) {
  __shared__ __align__(16) USH xs[4 * 64 * 64];   // 32KB, swizzled x tile
  __shared__ __align__(16) USH Hs[2][64 * 256];   // 64KB, XOR-swizzled, dbuf
  __shared__ float b1s[2048];
  __shared__ float b2s[2048];
  __shared__ float gse[512];                      // gse[e*64+n]  (transposed!)

  int tid = threadIdx.x;
  int wave = tid >> 6, lane = tid & 63;
  int quad = lane >> 4, l16 = lane & 15;
  int sw = l16 & 7;
  int rowBase = blockIdx.x * 64;

  // ---- prologue: x tile -> xs (swizzled); biases/gates -> LDS
#pragma unroll
  for (int it = 0; it < 4; ++it) {
    int i = it * 512 + tid;
    int kt = i >> 9, rem = i & 511;
    int r = rem >> 3, slot = rem & 7;
    int c8 = slot ^ (r & 7);
    gl2lds16(xb + (size_t)(rowBase + r) * 256 + kt * 64 + c8 * 8, xs + (size_t)i * 8);
  }

  // first expert's W1 fragments -> registers (in flight across the drain)
  bf16x8 wra[8], wrb[8];
  auto LDWH = [&](bf16x8* dst, const USH* We, int tb) {
#pragma unroll
    for (int k = 0; k < 2; ++k)
#pragma unroll
      for (int c = 0; c < 2; ++c)
#pragma unroll
        for (int i = 0; i < 2; ++i)
          dst[k * 4 + c * 2 + i] = *(const bf16x8*)(
              We + (size_t)(((tb + k) * 16 + wave * 2 + i) * 2 + c) * 512 + lane * 8);
  };
  LDWH(wra, w1f, 0);
  LDWH(wrb, w1f, 2);

#pragma unroll
  for (int t = 0; t < 4; ++t) {
    b1s[t * 512 + tid] = b1[t * 512 + tid];
    b2s[t * 512 + tid] = b2[t * 512 + tid];
  }
  {   // gse[e*64+n] = g[(rowBase+n)*8+e]
    int e = tid >> 6, n = tid & 63;
    gse[tid] = g[(size_t)(rowBase + n) * 8 + e];
  }

  // one-time full drain: xs/biases visible, first W1 set landed
  asm volatile("s_waitcnt vmcnt(0) lgkmcnt(0)" ::: "memory");
  __builtin_amdgcn_s_barrier();

  f32x4 oacc[4][2] = {};

#pragma unroll 1
  for (int e = 0; e < 8; ++e) {
    const USH* W2e = w2f + (size_t)e * 65536;
    const USH* W1n = w1f + (size_t)((e + 1) & 7) * 65536;
    f32x4 hacc[2][4] = {};

    // phase 1: H^T[h,n] = sum_c W1[c,h]*x[n,c]; wave owns h = wave*32..+31.
    // Weights already in wra/wrb; x frags from xs (LDS).
#pragma unroll
    for (int kt = 0; kt < 2; ++kt)
#pragma unroll
      for (int c = 0; c < 2; ++c) {
        int cs = ((c * 4 + quad) ^ sw) * 8;
        bf16x8 bv[4];
#pragma unroll
        for (int j = 0; j < 4; ++j)
          bv[j] = *(const bf16x8*)(xs + kt * 4096 + (j * 16 + l16) * 64 + cs);
#pragma unroll
        for (int i = 0; i < 2; ++i)
#pragma unroll
          for (int j = 0; j < 4; ++j)
            hacc[i][j] = __builtin_amdgcn_mfma_f32_16x16x32_bf16(
                wra[kt * 4 + c * 2 + i], bv[j], hacc[i][j], 0, 0, 0);
      }
    LDWH(wra, W2e, 0);            // refill wra with W2(e) ht=0,1
#pragma unroll
    for (int kt = 2; kt < 4; ++kt)
#pragma unroll
      for (int c = 0; c < 2; ++c) {
        int cs = ((c * 4 + quad) ^ sw) * 8;
        bf16x8 bv[4];
#pragma unroll
        for (int j = 0; j < 4; ++j)
          bv[j] = *(const bf16x8*)(xs + kt * 4096 + (j * 16 + l16) * 64 + cs);
#pragma unroll
        for (int i = 0; i < 2; ++i)
#pragma unroll
          for (int j = 0; j < 4; ++j)
            hacc[i][j] = __builtin_amdgcn_mfma_f32_16x16x32_bf16(
                wrb[(kt - 2) * 4 + c * 2 + i], bv[j], hacc[i][j], 0, 0, 0);
      }
    LDWH(wrb, W2e, 2);            // refill wrb with W2(e) ht=2,3

    // epilogue 1: Hs[e&1][n][h] = bf16(relu(hacc+b1)*g[n,e]); 4 consecutive h
    // per reg quad -> uint2 write, XOR-swizzled to match phase-2 A-frag reads.
    USH* Hb = &Hs[e & 1][0];
#pragma unroll
    for (int i = 0; i < 2; ++i) {
      int slot = (wave & 1) * 4 + i * 2 + (quad >> 1);   // (h>>3)&7
      int hb = wave * 32 + i * 16 + quad * 4;
#pragma unroll
      for (int j = 0; j < 4; ++j) {
        int n = j * 16 + l16;
        float gg = gse[e * 64 + n];
        USH w4[4];
#pragma unroll
        for (int r = 0; r < 4; ++r)
          w4[r] = f2bf(fmaxf(hacc[i][j][r] + b1s[e * 256 + hb + r], 0.0f) * gg);
        int off = n * 256 + (wave >> 1) * 64 + ((slot ^ (n & 7)) * 8) + (quad & 1) * 4;
        *(uint2*)(Hb + off) = *(const uint2*)w4;
      }
    }

    // single barrier per expert: LDS drain only -- weight prefetches (vmcnt)
    // stay in flight across it.
    asm volatile("s_waitcnt lgkmcnt(0)" ::: "memory");
    __builtin_amdgcn_s_barrier();

    // phase 2: out[n,d] += sum_h Hs[n,h]*W2[h,d]; wave owns d = wave*32..+31.
#pragma unroll
    for (int ht = 0; ht < 2; ++ht)
#pragma unroll
      for (int c = 0; c < 2; ++c) {
        int cs = ((c * 4 + quad) ^ sw) * 8;
        bf16x8 av[4];
#pragma unroll
        for (int i = 0; i < 4; ++i)
          av[i] = *(const bf16x8*)(Hb + (i * 16 + l16) * 256 + ht * 64 + cs);
#pragma unroll
        for (int i = 0; i < 4; ++i)
#pragma unroll
          for (int j = 0; j < 2; ++j)
            oacc[i][j] = __builtin_amdgcn_mfma_f32_16x16x32_bf16(
                av[i], wra[ht * 4 + c * 2 + j], oacc[i][j], 0, 0, 0);
      }
    LDWH(wra, W1n, 0);            // prefetch next expert's W1 kt=0,1
#pragma unroll
    for (int ht = 2; ht < 4; ++ht)
#pragma unroll
      for (int c = 0; c < 2; ++c) {
        int cs = ((c * 4 + quad) ^ sw) * 8;
        bf16x8 av[4];
#pragma unroll
        for (int i = 0; i < 4; ++i)
          av[i] = *(const bf16x8*)(Hb + (i * 16 + l16) * 256 + ht * 64 + cs);
#pragma unroll
        for (int i = 0; i < 4; ++i)
#pragma unroll
          for (int j = 0; j < 2; ++j)
            oacc[i][j] = __builtin_amdgcn_mfma_f32_16x16x32_bf16(
                av[i], wrb[(ht - 2) * 4 + c * 2 + j], oacc[i][j], 0, 0, 0);
      }
    LDWH(wrb, W1n, 2);            // prefetch next expert's W1 kt=2,3 (e=7: dummy)
  }

  // final epilogue: out = oacc + sum_e g[n,e]*b2[e,d]  (exact f32 bias)
#pragma unroll
  for (int i = 0; i < 4; ++i)
#pragma unroll
    for (int r = 0; r < 4; ++r) {
      int n = i * 16 + quad * 4 + r;
      size_t grow = (size_t)(rowBase + n) * 256;
#pragma unroll
      for (int j = 0; j < 2; ++j) {
        int d = wave * 32 + j * 16 + l16;
        float bias = 0.0f;
#pragma unroll
        for (int ee = 0; ee < 8; ++ee) bias += gse[ee * 64 + n] * b2s[ee * 256 + d];
        out[grow + d] = oacc[i][j][r] + bias;
      }
    }
}

// ---------------- launch ----------------

extern "C" void kernel_launch(void* const* d_in, const int* in_sizes, int n_in,
                              void* d_out, int out_size, void* d_ws, size_t ws_size,
                              hipStream_t stream) {
  const float* x   = (const float*)d_in[0];
  const float* Wg1 = (const float*)d_in[1];
  const float* bg1 = (const float*)d_in[2];
  const float* Wg2 = (const float*)d_in[3];
  const float* bg2 = (const float*)d_in[4];
  const float* W1  = (const float*)d_in[5];
  const float* b1  = (const float*)d_in[6];
  const float* W2  = (const float*)d_in[7];
  const float* b2  = (const float*)d_in[8];
  float* out = (float*)d_out;

  char* ws = (char*)d_ws;
  USH*   xb  = (USH*)(ws);
  USH*   w1f = (USH*)(ws + 8388608);
  USH*   wg1t = (USH*)(ws + 9437184);
  USH*   w2f = (USH*)(ws + 9502720);
  float* g   = (float*)(ws + 10584064);

  hipLaunchKernelGGL(k_prep, dim3(2312), dim3(256), 0, stream,
                     x, Wg1, W1, W2, xb, wg1t, w1f, w2f);
  hipLaunchKernelGGL(k_gate, dim3(512), dim3(256), 0, stream,
                     xb, wg1t, bg1, Wg2, bg2, g);
  hipLaunchKernelGGL(k_moe, dim3(256), dim3(512), 0, stream,
                     xb, w1f, w2f, b1, b2, g, out);
}

// Round 7
// 123.155 us; speedup vs baseline: 1.3347x; 1.0606x over previous
//
#include <hip/hip_runtime.h>

// MoE dense: N=16384, D=256, E=8, H=128 (gate hidden), expert hidden 256.
// R14b: R14 with the launch-call typo fixed (Wg2). Eliminate the non-moe
// 75us: R13's k_moe=55 of 130.6 total -> k_prep (2312 blocks, 30MB f32
// traffic) + k_gate + dispatch gaps were the majority.
//  - gate is row-local -> computed inside k_moe's prologue (MFMA path with
//    wg1f fragment-major weights; numerics bitwise-identical to old k_gate).
//  - xb removed: each x element is used by exactly ONE block -> k_moe reads
//    x f32 directly, casts in-reg (same f2bf), ds_writes swizzled xs.
//  - k_prep now weights-only: 264 blocks (w1f 128, w2f 128, wg1f 8).
//  - k_moe expert loop byte-identical to R13 (clean attribution).
// Workspace:
//   w1f  fragment-major W1 @ 8388608   (1MB)
//   wg1f fragment-major Wg1 @ 9437184  (64KB)
//   w2f  fragment-major W2 @ 9502720   (1MB)

typedef unsigned short USH;
typedef float f32x4 __attribute__((ext_vector_type(4)));
typedef __bf16 bf16x8 __attribute__((ext_vector_type(8)));

__device__ __forceinline__ USH f2bf(float f) {
  unsigned int u = __float_as_uint(f);
  u += 0x7fffu + ((u >> 16) & 1u);   // RNE
  return (USH)(u >> 16);
}

// ---------------- prep (weights only) ----------------
// w1f fragment layout: value W1[e][c][h]; t=h>>4, kt=c>>6, ch=(c>>5)&1,
//   q=(c>>3)&3, u=c&7:  idx = ((e*64+kt*16+t)*2+ch)*512 + (q*16+(h&15))*8 + u
// w2f same with (h->k-role, d->out-role): value W2[e][h][d].
// wg1f: value Wg1[c][h], h in [0,128): idx = ((kt*8+t)*2+ch)*512 + ...

__global__ __launch_bounds__(256) void k_prep(
    const float* __restrict__ Wg1,
    const float* __restrict__ W1,
    const float* __restrict__ W2,
    USH* __restrict__ w1f, USH* __restrict__ w2f, USH* __restrict__ wg1f) {
  __shared__ float T[64][65];
  int b = blockIdx.x, tid = threadIdx.x;

  if (b < 128) {                // w1f
    int e = b >> 4, tl = b & 15;
    int c0 = (tl >> 2) * 64, h0 = (tl & 3) * 64;
    const float* src = W1 + (size_t)e * 65536;
#pragma unroll
    for (int p = 0; p < 4; ++p) {
      int r = p * 16 + (tid >> 4), d4 = (tid & 15) * 4;
      float4 v = *(const float4*)(src + (size_t)(c0 + r) * 256 + h0 + d4);
      T[r][d4] = v.x; T[r][d4 + 1] = v.y; T[r][d4 + 2] = v.z; T[r][d4 + 3] = v.w;
    }
    __syncthreads();
#pragma unroll
    for (int p = 0; p < 4; ++p) {
      int hr = p * 16 + (tid >> 4), c4 = (tid & 15) * 4;
      USH w[4];
#pragma unroll
      for (int j = 0; j < 4; ++j) w[j] = f2bf(T[c4 + j][hr]);   // W1[e][c0+c4+j][h0+hr]
      int h = h0 + hr;
      int t = h >> 4, lh = h & 15;
      int kt = c0 >> 6, ch = (c4 >> 5) & 1, q = (c4 >> 3) & 3, u0 = c4 & 7;
      size_t idx = ((size_t)((e * 64 + kt * 16 + t) * 2 + ch)) * 512 + (q * 16 + lh) * 8 + u0;
      *(uint2*)(w1f + idx) = *(const uint2*)w;
    }
  } else if (b < 256) {         // w2f
    int bp = b - 128;
    int e = bp >> 4, tl = bp & 15;
    int h0 = (tl >> 2) * 64, d0 = (tl & 3) * 64;
    const float* src = W2 + (size_t)e * 65536;
#pragma unroll
    for (int p = 0; p < 4; ++p) {
      int r = p * 16 + (tid >> 4), d4 = (tid & 15) * 4;
      float4 v = *(const float4*)(src + (size_t)(h0 + r) * 256 + d0 + d4);
      T[r][d4] = v.x; T[r][d4 + 1] = v.y; T[r][d4 + 2] = v.z; T[r][d4 + 3] = v.w;
    }
    __syncthreads();
#pragma unroll
    for (int p = 0; p < 4; ++p) {
      int dr = p * 16 + (tid >> 4), h4 = (tid & 15) * 4;
      USH w[4];
#pragma unroll
      for (int j = 0; j < 4; ++j) w[j] = f2bf(T[h4 + j][dr]);   // W2[e][h0+h4+j][d0+dr]
      int d = d0 + dr;
      int t = d >> 4, ld = d & 15;
      int ht = h0 >> 6, ch = (h4 >> 5) & 1, q = (h4 >> 3) & 3, u0 = h4 & 7;
      size_t idx = ((size_t)((e * 64 + ht * 16 + t) * 2 + ch)) * 512 + (q * 16 + ld) * 8 + u0;
      *(uint2*)(w2f + idx) = *(const uint2*)w;
    }
  } else {                      // wg1f (8 blocks)
    int bp = b - 256;
    int c0 = (bp >> 1) * 64, h0 = (bp & 1) * 64;
#pragma unroll
    for (int p = 0; p < 4; ++p) {
      int r = p * 16 + (tid >> 4), d4 = (tid & 15) * 4;
      float4 v = *(const float4*)(Wg1 + (size_t)(c0 + r) * 128 + h0 + d4);
      T[r][d4] = v.x; T[r][d4 + 1] = v.y; T[r][d4 + 2] = v.z; T[r][d4 + 3] = v.w;
    }
    __syncthreads();
#pragma unroll
    for (int p = 0; p < 4; ++p) {
      int hr = p * 16 + (tid >> 4), c4 = (tid & 15) * 4;
      USH w[4];
#pragma unroll
      for (int j = 0; j < 4; ++j) w[j] = f2bf(T[c4 + j][hr]);   // Wg1[c0+c4+j][h0+hr]
      int h = h0 + hr;
      int t = h >> 4, lh = h & 15;
      int kt = c0 >> 6, ch = (c4 >> 5) & 1, q = (c4 >> 3) & 3, u0 = c4 & 7;
      size_t idx = ((size_t)((kt * 8 + t) * 2 + ch)) * 512 + (q * 16 + lh) * 8 + u0;
      *(uint2*)(wg1f + idx) = *(const uint2*)w;
    }
  }
}

// ---------------- fused gate + experts (256 blocks x 64 rows, 512 thr) ------

__global__ __launch_bounds__(512) void k_moe(const float* __restrict__ x,
                                             const USH* __restrict__ w1f,
                                             const USH* __restrict__ w2f,
                                             const USH* __restrict__ wg1f,
                                             const float* __restrict__ wg2,
                                             const float* __restrict__ bg1,
                                             const float* __restrict__ bg2,
                                             const float* __restrict__ b1,
                                             const float* __restrict__ b2,
                                             float* __restrict__ out) {
  __shared__ __align__(16) USH xs[4 * 64 * 64];   // 32KB, swizzled x tile
  __shared__ __align__(16) USH Hs[2][64 * 256];   // 64KB dbuf; Hs[0] doubles as hgs
  __shared__ float b1s[2048];
  __shared__ float b2s[2048];
  __shared__ float gse[512];                      // gse[e*64+n]
  __shared__ float wg2t[8 * 132];                 // wg2t[e][k], padded
  __shared__ float lgg[512];
  __shared__ float bg1s[128];
  __shared__ float bg2g[8];

  int tid = threadIdx.x;
  int wave = tid >> 6, lane = tid & 63;
  int quad = lane >> 4, l16 = lane & 15;
  int sw = l16 & 7;
  int rowBase = blockIdx.x * 64;
  float* hgs = (float*)&Hs[0][0];                 // 64x128 f32, slot-swizzled

  // ---- prologue: x f32 -> bf16 -> xs (swizzled); gate/bias constants
#pragma unroll
  for (int it = 0; it < 4; ++it) {
    int i = it * 512 + tid;
    int kt = i >> 9, rem = i & 511;
    int r = rem >> 3, slot = rem & 7;
    int c8 = slot ^ (r & 7);
    const float* sp = x + (size_t)(rowBase + r) * 256 + kt * 64 + c8 * 8;
    float4 a = *(const float4*)sp;
    float4 bq = *(const float4*)(sp + 4);
    USH v[8];
    v[0] = f2bf(a.x);  v[1] = f2bf(a.y);  v[2] = f2bf(a.z);  v[3] = f2bf(a.w);
    v[4] = f2bf(bq.x); v[5] = f2bf(bq.y); v[6] = f2bf(bq.z); v[7] = f2bf(bq.w);
    *(uint4*)(xs + (size_t)i * 8) = *(const uint4*)v;
  }
#pragma unroll
  for (int t = 0; t < 4; ++t) {
    b1s[t * 512 + tid] = b1[t * 512 + tid];
    b2s[t * 512 + tid] = b2[t * 512 + tid];
  }
  for (int t = tid; t < 1024; t += 512) wg2t[(t & 7) * 132 + (t >> 3)] = wg2[t];
  if (tid < 128) bg1s[tid] = bg1[tid];
  if (tid < 8) bg2g[tid] = bg2[tid];

  // first expert's W1 fragments -> registers (in flight during the gate)
  bf16x8 wra[8], wrb[8];
  auto LDWH = [&](bf16x8* dst, const USH* We, int tb) {
#pragma unroll
    for (int k = 0; k < 2; ++k)
#pragma unroll
      for (int c = 0; c < 2; ++c)
#pragma unroll
        for (int i = 0; i < 2; ++i)
          dst[k * 4 + c * 2 + i] = *(const bf16x8*)(
              We + (size_t)(((tb + k) * 16 + wave * 2 + i) * 2 + c) * 512 + lane * 8);
  };
  LDWH(wra, w1f, 0);
  LDWH(wrb, w1f, 2);

  asm volatile("s_waitcnt lgkmcnt(0)" ::: "memory");
  __builtin_amdgcn_s_barrier();

  // ---- gate stage 1: hg^T[h,n] = sum_c Wg1[c,h]*x[n,c]; wave owns 16 h.
  {
    f32x4 hg4[4] = {};
#pragma unroll
    for (int kt = 0; kt < 4; ++kt)
#pragma unroll
      for (int c = 0; c < 2; ++c) {
        int cs = ((c * 4 + quad) ^ sw) * 8;
        bf16x8 av = *(const bf16x8*)(wg1f + (size_t)((kt * 8 + wave) * 2 + c) * 512 + lane * 8);
        bf16x8 bv[4];
#pragma unroll
        for (int j = 0; j < 4; ++j)
          bv[j] = *(const bf16x8*)(xs + kt * 4096 + (j * 16 + l16) * 64 + cs);
#pragma unroll
        for (int j = 0; j < 4; ++j)
          hg4[j] = __builtin_amdgcn_mfma_f32_16x16x32_bf16(av, bv[j], hg4[j], 0, 0, 0);
      }
    // hgs[n][h] = relu(hg + bg1), h-slot XOR-swizzled (slot = (h>>2)^(n&7))
    int hb = wave * 16 + quad * 4;
    int slotbase = wave * 4 + quad;
#pragma unroll
    for (int j = 0; j < 4; ++j) {
      int n = j * 16 + l16;
      int slot = slotbase ^ (n & 7);
      f32x4 v;
#pragma unroll
      for (int r = 0; r < 4; ++r) v[r] = fmaxf(hg4[j][r] + bg1s[hb + r], 0.0f);
      *(f32x4*)(hgs + n * 128 + slot * 4) = v;
    }
  }
  asm volatile("s_waitcnt lgkmcnt(0)" ::: "memory");
  __builtin_amdgcn_s_barrier();

  // ---- gate stage 2: logits[n][e] (f32, same k-order as old k_gate)
  {
    int n = tid >> 3, eg = tid & 7;
    float s = bg2g[eg];
#pragma unroll
    for (int k4 = 0; k4 < 32; ++k4) {
      int slot = k4 ^ (n & 7);
      f32x4 hv = *(const f32x4*)(hgs + n * 128 + slot * 4);
      const float* wv = wg2t + eg * 132 + k4 * 4;
      s += hv[0] * wv[0]; s += hv[1] * wv[1]; s += hv[2] * wv[2]; s += hv[3] * wv[3];
    }
    lgg[tid] = s;
  }
  asm volatile("s_waitcnt lgkmcnt(0)" ::: "memory");
  __builtin_amdgcn_s_barrier();

  if (tid < 64) {               // softmax over 8 experts
    float l[8]; float m = -1e30f;
#pragma unroll
    for (int e = 0; e < 8; ++e) { l[e] = lgg[tid * 8 + e]; m = fmaxf(m, l[e]); }
    float s = 0.0f;
#pragma unroll
    for (int e = 0; e < 8; ++e) { l[e] = expf(l[e] - m); s += l[e]; }
    float inv = 1.0f / s;
#pragma unroll
    for (int e = 0; e < 8; ++e) gse[e * 64 + tid] = l[e] * inv;
  }
  asm volatile("s_waitcnt lgkmcnt(0)" ::: "memory");
  __builtin_amdgcn_s_barrier();   // gse visible; hgs (Hs[0]) now dead

  // ---- expert loop (R13 verbatim) ----
  f32x4 oacc[4][2] = {};

#pragma unroll 1
  for (int e = 0; e < 8; ++e) {
    const USH* W2e = w2f + (size_t)e * 65536;
    const USH* W1n = w1f + (size_t)((e + 1) & 7) * 65536;
    f32x4 hacc[2][4] = {};

    // phase 1: H^T[h,n] = sum_c W1[c,h]*x[n,c]; wave owns h = wave*32..+31.
#pragma unroll
    for (int kt = 0; kt < 2; ++kt)
#pragma unroll
      for (int c = 0; c < 2; ++c) {
        int cs = ((c * 4 + quad) ^ sw) * 8;
        bf16x8 bv[4];
#pragma unroll
        for (int j = 0; j < 4; ++j)
          bv[j] = *(const bf16x8*)(xs + kt * 4096 + (j * 16 + l16) * 64 + cs);
#pragma unroll
        for (int i = 0; i < 2; ++i)
#pragma unroll
          for (int j = 0; j < 4; ++j)
            hacc[i][j] = __builtin_amdgcn_mfma_f32_16x16x32_bf16(
                wra[kt * 4 + c * 2 + i], bv[j], hacc[i][j], 0, 0, 0);
      }
    LDWH(wra, W2e, 0);            // refill wra with W2(e) ht=0,1
#pragma unroll
    for (int kt = 2; kt < 4; ++kt)
#pragma unroll
      for (int c = 0; c < 2; ++c) {
        int cs = ((c * 4 + quad) ^ sw) * 8;
        bf16x8 bv[4];
#pragma unroll
        for (int j = 0; j < 4; ++j)
          bv[j] = *(const bf16x8*)(xs + kt * 4096 + (j * 16 + l16) * 64 + cs);
#pragma unroll
        for (int i = 0; i < 2; ++i)
#pragma unroll
          for (int j = 0; j < 4; ++j)
            hacc[i][j] = __builtin_amdgcn_mfma_f32_16x16x32_bf16(
                wrb[(kt - 2) * 4 + c * 2 + i], bv[j], hacc[i][j], 0, 0, 0);
      }
    LDWH(wrb, W2e, 2);            // refill wrb with W2(e) ht=2,3

    // epilogue 1: Hs[e&1][n][h] = bf16(relu(hacc+b1)*g[n,e])
    USH* Hb = &Hs[e & 1][0];
#pragma unroll
    for (int i = 0; i < 2; ++i) {
      int slot = (wave & 1) * 4 + i * 2 + (quad >> 1);   // (h>>3)&7
      int hb = wave * 32 + i * 16 + quad * 4;
#pragma unroll
      for (int j = 0; j < 4; ++j) {
        int n = j * 16 + l16;
        float gg = gse[e * 64 + n];
        USH w4[4];
#pragma unroll
        for (int r = 0; r < 4; ++r)
          w4[r] = f2bf(fmaxf(hacc[i][j][r] + b1s[e * 256 + hb + r], 0.0f) * gg);
        int off = n * 256 + (wave >> 1) * 64 + ((slot ^ (n & 7)) * 8) + (quad & 1) * 4;
        *(uint2*)(Hb + off) = *(const uint2*)w4;
      }
    }

    // single barrier per expert: LDS drain only; weight prefetches stay live.
    asm volatile("s_waitcnt lgkmcnt(0)" ::: "memory");
    __builtin_amdgcn_s_barrier();

    // phase 2: out[n,d] += sum_h Hs[n,h]*W2[h,d]; wave owns d = wave*32..+31.
#pragma unroll
    for (int ht = 0; ht < 2; ++ht)
#pragma unroll
      for (int c = 0; c < 2; ++c) {
        int cs = ((c * 4 + quad) ^ sw) * 8;
        bf16x8 av[4];
#pragma unroll
        for (int i = 0; i < 4; ++i)
          av[i] = *(const bf16x8*)(Hb + (i * 16 + l16) * 256 + ht * 64 + cs);
#pragma unroll
        for (int i = 0; i < 4; ++i)
#pragma unroll
          for (int j = 0; j < 2; ++j)
            oacc[i][j] = __builtin_amdgcn_mfma_f32_16x16x32_bf16(
                av[i], wra[ht * 4 + c * 2 + j], oacc[i][j], 0, 0, 0);
      }
    LDWH(wra, W1n, 0);            // prefetch next expert's W1 kt=0,1
#pragma unroll
    for (int ht = 2; ht < 4; ++ht)
#pragma unroll
      for (int c = 0; c < 2; ++c) {
        int cs = ((c * 4 + quad) ^ sw) * 8;
        bf16x8 av[4];
#pragma unroll
        for (int i = 0; i < 4; ++i)
          av[i] = *(const bf16x8*)(Hb + (i * 16 + l16) * 256 + ht * 64 + cs);
#pragma unroll
        for (int i = 0; i < 4; ++i)
#pragma unroll
          for (int j = 0; j < 2; ++j)
            oacc[i][j] = __builtin_amdgcn_mfma_f32_16x16x32_bf16(
                av[i], wrb[(ht - 2) * 4 + c * 2 + j], oacc[i][j], 0, 0, 0);
      }
    LDWH(wrb, W1n, 2);            // prefetch next expert's W1 kt=2,3 (e=7: dummy)
  }

  // final epilogue: out = oacc + sum_e g[n,e]*b2[e,d]  (exact f32 bias)
#pragma unroll
  for (int i = 0; i < 4; ++i)
#pragma unroll
    for (int r = 0; r < 4; ++r) {
      int n = i * 16 + quad * 4 + r;
      size_t grow = (size_t)(rowBase + n) * 256;
#pragma unroll
      for (int j = 0; j < 2; ++j) {
        int d = wave * 32 + j * 16 + l16;
        float bias = 0.0f;
#pragma unroll
        for (int ee = 0; ee < 8; ++ee) bias += gse[ee * 64 + n] * b2s[ee * 256 + d];
        out[grow + d] = oacc[i][j][r] + bias;
      }
    }
}

// ---------------- launch ----------------

extern "C" void kernel_launch(void* const* d_in, const int* in_sizes, int n_in,
                              void* d_out, int out_size, void* d_ws, size_t ws_size,
                              hipStream_t stream) {
  const float* x   = (const float*)d_in[0];
  const float* Wg1 = (const float*)d_in[1];
  const float* bg1 = (const float*)d_in[2];
  const float* Wg2 = (const float*)d_in[3];
  const float* bg2 = (const float*)d_in[4];
  const float* W1  = (const float*)d_in[5];
  const float* b1  = (const float*)d_in[6];
  const float* W2  = (const float*)d_in[7];
  const float* b2  = (const float*)d_in[8];
  float* out = (float*)d_out;

  char* ws = (char*)d_ws;
  USH* w1f  = (USH*)(ws + 8388608);
  USH* wg1f = (USH*)(ws + 9437184);
  USH* w2f  = (USH*)(ws + 9502720);

  hipLaunchKernelGGL(k_prep, dim3(264), dim3(256), 0, stream,
                     Wg1, W1, W2, w1f, w2f, wg1f);
  hipLaunchKernelGGL(k_moe, dim3(256), dim3(512), 0, stream,
                     x, w1f, w2f, wg1f, Wg2, bg1, bg2, b1, b2, out);
}